// Round 7
// baseline (353.175 us; speedup 1.0000x reference)
//
#include <hip/hip_runtime.h>
#include <hip/hip_bf16.h>

typedef __attribute__((ext_vector_type(4))) float f32x4;
typedef __attribute__((ext_vector_type(8))) short s16x8;
typedef unsigned short u16;
typedef unsigned int u32;

#define MFMA16 __builtin_amdgcn_mfma_f32_16x16x32_bf16

// global_load_lds: LDS dest is wave-uniform base + lane*16 (linear!), global src per-lane.
#define GLL16(g, l)                                                        \
  __builtin_amdgcn_global_load_lds(                                        \
      (const __attribute__((address_space(1))) void*)(g),                  \
      (__attribute__((address_space(3))) void*)(l), 16, 0, 0)

__device__ __forceinline__ u16 f2b(float f) {
  u32 x = __builtin_bit_cast(u32, f);
  u32 r = (x + 0x7fffu + ((x >> 16) & 1u)) >> 16;
  return (u16)r;
}
__device__ __forceinline__ float b2f(u16 u) {
  u32 x = ((u32)u) << 16;
  return __builtin_bit_cast(float, x);
}

// ---------- fp32 -> bf16 elementwise (x) ----------
__global__ __launch_bounds__(256) void k_cvt(const float* __restrict__ in, u16* __restrict__ out) {
  size_t i = ((size_t)blockIdx.x * 256 + threadIdx.x) * 4;
  float4 v = *(const float4*)(in + i);
  ushort4 o; o.x = f2b(v.x); o.y = f2b(v.y); o.z = f2b(v.z); o.w = f2b(v.w);
  *(ushort4*)(out + i) = o;
}

// ---------- transpose + convert: in (R x C) fp32 -> out (C x R) bf16 ----------
__global__ __launch_bounds__(256) void k_tconv(const float* __restrict__ in, u16* __restrict__ out,
                                               int R, int C) {
  __shared__ u16 tile[64][72];
  int c0 = blockIdx.x * 64, r0 = blockIdx.y * 64;
  int t = threadIdx.x;
#pragma unroll
  for (int p = 0; p < 4; ++p) {
    int idx = p * 1024 + t * 4;
    int row = idx >> 6, col = idx & 63;
    float4 v = *(const float4*)&in[(size_t)(r0 + row) * C + c0 + col];
    tile[row][col]     = f2b(v.x);
    tile[row][col + 1] = f2b(v.y);
    tile[row][col + 2] = f2b(v.z);
    tile[row][col + 3] = f2b(v.w);
  }
  __syncthreads();
#pragma unroll
  for (int p = 0; p < 4; ++p) {
    int idx = p * 1024 + t * 4;
    int row = idx >> 6, col = idx & 63;   // row: c-dim, col: r-dim
    ushort4 o;
    o.x = tile[col][row]; o.y = tile[col + 1][row];
    o.z = tile[col + 2][row]; o.w = tile[col + 3][row];
    *(ushort4*)&out[(size_t)(c0 + row) * R + r0 + col] = o;
  }
}

// ---------- bf16 transpose per (b,h): (2048 s x 128 d) -> (128 d x 2048 s) ----------
__global__ __launch_bounds__(256) void k_trv(const u16* __restrict__ v, u16* __restrict__ vt) {
  __shared__ u16 tile[64][72];
  int bh = blockIdx.z;
  int s0 = blockIdx.x * 64, d0 = blockIdx.y * 64;
  const u16* src = v + (size_t)bh * 2048 * 128;
  u16* dst = vt + (size_t)bh * 2048 * 128;
  int t = threadIdx.x;
#pragma unroll
  for (int p = 0; p < 4; ++p) {
    int idx = p * 1024 + t * 4;
    int row = idx >> 6, col = idx & 63;
    ushort4 x = *(const ushort4*)&src[(size_t)(s0 + row) * 128 + d0 + col];
    tile[row][col] = x.x; tile[row][col + 1] = x.y;
    tile[row][col + 2] = x.z; tile[row][col + 3] = x.w;
  }
  __syncthreads();
#pragma unroll
  for (int p = 0; p < 4; ++p) {
    int idx = p * 1024 + t * 4;
    int row = idx >> 6, col = idx & 63;   // row: d-local, col: s-local
    ushort4 o;
    o.x = tile[col][row]; o.y = tile[col + 1][row];
    o.z = tile[col + 2][row]; o.w = tile[col + 3][row];
    *(ushort4*)&dst[(size_t)(d0 + row) * 2048 + s0 + col] = o;
  }
}

// ---------- RoPE trig table ----------
__global__ __launch_bounds__(256) void k_trig(float2* __restrict__ tab) {
  int t = blockIdx.x * 256 + threadIdx.x;      // 2048*64
  int s = t >> 6, i = t & 63;
  float inv = expf(-(float)i * (9.210340371976184f / 64.f)); // ln(10000)
  float a = (float)s * inv;
  float sn, cs;
  sincosf(a, &sn, &cs);
  tab[t] = make_float2(cs, sn);
}

// ---------- RoPE in-place on q (y=0) / k (y=1), (B*H, S, 128) bf16 ----------
__global__ __launch_bounds__(256) void k_rope(u16* __restrict__ q, u16* __restrict__ k,
                                              const float2* __restrict__ tab) {
  u16* ptr = blockIdx.y ? k : q;
  size_t tid = (size_t)blockIdx.x * 256 + threadIdx.x;  // 32*2048*16
  int g = (int)(tid & 15);
  int s = (int)((tid >> 4) & 2047);
  int bh = (int)(tid >> 15);
  size_t base = ((size_t)bh * 2048 + s) * 128 + (size_t)g * 8;
  uint4 dv = *(const uint4*)(ptr + base);
  u16* pu = (u16*)&dv;
  const float2* tb = &tab[s * 64 + g * 4];
#pragma unroll
  for (int j = 0; j < 4; ++j) {
    float xe = b2f(pu[2 * j]), xo = b2f(pu[2 * j + 1]);
    float c = tb[j].x, sn = tb[j].y;
    pu[2 * j]     = f2b(xe * c - xo * sn);
    pu[2 * j + 1] = f2b(xe * sn + xo * c);
  }
  *(uint4*)(ptr + base) = dv;
}

// ---------- 8-phase-style GEMM (T2+T3+T4+T5): BM=128, BN=256, BK=64, 8 waves (2x4) ----------
// Per K-step: 2 phases {8 ds_read (+6 GLL at P0) -> s_barrier -> lgkmcnt(0) -> 16 MFMA -> barrier};
// K-tile t+1 staged entirely at P0 of t into buf^1; boundary = vmcnt(0)+barrier (loads ~1.5 phases old).
// LDS XOR swizzle (rule #21): linear GLL dest + inverse-swizzled global source + same XOR on read;
// byte ^= ((row&7)<<4) -> ds_read lanes 0-7 hit 8 distinct 16B slots (conflict-free).
// MODE 0: scatter bf16 into q/k/v (B,H,S,128); MODE 1: fp32 C.
template <int MODE>
__global__ __launch_bounds__(512) void k_gemm8(const u16* __restrict__ A, const u16* __restrict__ Bt,
                                               u16* __restrict__ qo, u16* __restrict__ ko,
                                               u16* __restrict__ vo, float* __restrict__ C) {
  constexpr int K = 2048;
  constexpr int NT = K / 64;
  __shared__ u16 sA[2][128 * 64];   // 2 x 16 KB
  __shared__ u16 sB[2][256 * 64];   // 2 x 32 KB
  int tid = threadIdx.x;
  int lane = tid & 63, w = tid >> 6;
  int wr = w >> 2, wc = w & 3;               // 2(M) x 4(N) wave grid, 64x64 per wave
  int lr = lane & 15, lg = lane >> 4;

  // XCD-bijective block swizzle (nwg % 8 == 0 for both instantiations)
  int id = blockIdx.y * gridDim.x + blockIdx.x;
  int cpx = (gridDim.x * gridDim.y) >> 3;
  int swz = (id & 7) * cpx + (id >> 3);
  int n0 = (swz % gridDim.x) * 256;
  int m0 = (swz / gridDim.x) * 128;

  // staging: per GLL round, thread covers row = r*64 + tid>>3, linear col byte (tid&7)*16;
  // global source col pre-swizzled by ((row&7)<<4) = ((tid>>3)&7)<<4  (rounds are 64-row aligned)
  int srow = tid >> 3;
  int swzcolb = ((tid & 7) << 4) ^ ((srow & 7) << 4);
  const char* gA = (const char*)(A + (size_t)(m0 + srow) * K) + swzcolb;
  const char* gB = (const char*)(Bt + (size_t)(n0 + srow) * K) + swzcolb;

#define STAGE8(buf, k0)                                                      \
  {                                                                          \
    _Pragma("unroll") for (int rb = 0; rb < 4; ++rb)                         \
        GLL16(gB + ((size_t)rb * 64 * K + (k0)) * 2,                         \
              (char*)&sB[buf][0] + rb * 8192 + tid * 16);                    \
    _Pragma("unroll") for (int ra = 0; ra < 2; ++ra)                         \
        GLL16(gA + ((size_t)ra * 64 * K + (k0)) * 2,                         \
              (char*)&sA[buf][0] + ra * 8192 + tid * 16);                    \
  }

  // fragment read addressing: row = {wr|wc}*64 + i*16 + lr (row&7 == lr&7);
  // physical col byte = (ks*64 | lg*16) ^ ((lr&7)<<4) = colb0 ^ (ks<<6)
  int colb0 = (lg << 4) ^ ((lr & 7) << 4);
  int aRowByte = (wr * 64 + lr) * 128;
  int bRowByte = (wc * 64 + lr) * 128;

  f32x4 acc[4][4] = {};

  STAGE8(0, 0);
  asm volatile("s_waitcnt vmcnt(0)" ::: "memory");
  __builtin_amdgcn_s_barrier();

  for (int t = 0; t < NT; ++t) {
    int cur = t & 1;
    const char* sAb = (const char*)&sA[0][0] + cur * (128 * 64 * 2);
    const char* sBb = (const char*)&sB[0][0] + cur * (256 * 64 * 2);
    if (t + 1 < NT) STAGE8(cur ^ 1, (t + 1) * 64);
    s16x8 af[4], bf[4];
    // ---- phase 0 (ks=0) ----
#pragma unroll
    for (int i = 0; i < 4; ++i) af[i] = *(const s16x8*)(sAb + aRowByte + i * 2048 + colb0);
#pragma unroll
    for (int i = 0; i < 4; ++i) bf[i] = *(const s16x8*)(sBb + bRowByte + i * 2048 + colb0);
    __builtin_amdgcn_s_barrier();
    asm volatile("s_waitcnt lgkmcnt(0)" ::: "memory");
    __builtin_amdgcn_sched_barrier(0);
    __builtin_amdgcn_s_setprio(1);
#pragma unroll
    for (int mi = 0; mi < 4; ++mi)
#pragma unroll
      for (int ni = 0; ni < 4; ++ni)
        acc[mi][ni] = MFMA16(af[mi], bf[ni], acc[mi][ni], 0, 0, 0);
    __builtin_amdgcn_s_setprio(0);
    __builtin_amdgcn_s_barrier();
    // ---- phase 1 (ks=1) ----
#pragma unroll
    for (int i = 0; i < 4; ++i) af[i] = *(const s16x8*)(sAb + aRowByte + i * 2048 + (colb0 ^ 64));
#pragma unroll
    for (int i = 0; i < 4; ++i) bf[i] = *(const s16x8*)(sBb + bRowByte + i * 2048 + (colb0 ^ 64));
    __builtin_amdgcn_s_barrier();
    asm volatile("s_waitcnt lgkmcnt(0)" ::: "memory");
    __builtin_amdgcn_sched_barrier(0);
    __builtin_amdgcn_s_setprio(1);
#pragma unroll
    for (int mi = 0; mi < 4; ++mi)
#pragma unroll
      for (int ni = 0; ni < 4; ++ni)
        acc[mi][ni] = MFMA16(af[mi], bf[ni], acc[mi][ni], 0, 0, 0);
    __builtin_amdgcn_s_setprio(0);
    asm volatile("s_waitcnt vmcnt(0)" ::: "memory");   // next K-tile staged (issued at P0)
    __builtin_amdgcn_s_barrier();
  }
#undef STAGE8

  if constexpr (MODE == 0) {
#pragma unroll
    for (int ni = 0; ni < 4; ++ni) {
      int n = n0 + wc * 64 + ni * 16 + lr;
      int which = n >> 11;
      int h = (n >> 7) & 15;
      int d = n & 127;
      u16* dst = which == 0 ? qo : (which == 1 ? ko : vo);
#pragma unroll
      for (int mi = 0; mi < 4; ++mi)
#pragma unroll
        for (int r = 0; r < 4; ++r) {
          int m = m0 + wr * 64 + mi * 16 + lg * 4 + r;
          int b = m >> 11, s = m & 2047;
          dst[(((size_t)b * 16 + h) * 2048 + s) * 128 + d] = f2b(acc[mi][ni][r]);
        }
    }
  } else {
#pragma unroll
    for (int mi = 0; mi < 4; ++mi)
#pragma unroll
      for (int ni = 0; ni < 4; ++ni)
#pragma unroll
        for (int r = 0; r < 4; ++r) {
          int m = m0 + wr * 64 + mi * 16 + lg * 4 + r;
          int n = n0 + wc * 64 + ni * 16 + lr;
          C[(size_t)m * 2048 + n] = acc[mi][ni][r];
        }
  }
}

// ---------- Flash attention (causal): GLL double-buffered K/V staging ----------
__global__ __launch_bounds__(256) void k_attn(const u16* __restrict__ q, const u16* __restrict__ k,
                                              const u16* __restrict__ vt, u16* __restrict__ y) {
  constexpr int S = 2048, HD = 128;
  __shared__ u16 kt[2][64][128];   // 2 x 16 KB (kv x d), linear
  __shared__ u16 vtl[2][128][64];  // 2 x 16 KB (d x kv), linear
  __shared__ u16 pl[4][16][72];    // per-wave P (16 q x 64 kv)
  int bh = blockIdx.x;
  int qt = (gridDim.y - 1) - blockIdx.y;   // biggest q-tiles dispatched first (LPT)
  int q0 = qt * 64;
  int t = threadIdx.x, lane = t & 63, w = t >> 6;
  int lr = lane & 15, lg = lane >> 4;
  const size_t base = (size_t)bh * S * HD;
  const u16* kbh = k + base;
  const u16* vbh = vt + base;

  int kr_l = ((w * 4) << 2) + (lane >> 4);          // K row for instr i=0 (add 4*i)
  int kcb_base = (lane & 15) << 4;                  // linear byte col in K row
  int vr_l = ((w * 4) << 3) + (lane >> 3);          // V row for instr i=0 (add 8*i)
  int vcb_base = (lane & 7) << 4;                   // linear byte col in V row

  s16x8 aq[4];
  {
    size_t qrow = base + (size_t)(q0 + w * 16 + lr) * HD;
#pragma unroll
    for (int i = 0; i < 4; ++i) aq[i] = *(const s16x8*)&q[qrow + i * 32 + lg * 8];
  }
  f32x4 o[8] = {};
  float mrow[4] = {-INFINITY, -INFINITY, -INFINITY, -INFINITY};
  float lsum[4] = {};
  const float scale = 0.08838834764831845f;
  int kv_end = q0 + 64;

#define STAGE_KV(buf, kv)                                                             \
  {                                                                                   \
    _Pragma("unroll")                                                                 \
    for (int i = 0; i < 4; ++i) {                                                     \
      int kr = kr_l + 4 * i;                                                          \
      int kcb = kcb_base ^ ((kr & 7) << 4);                                           \
      GLL16((const char*)(kbh + (size_t)((kv) + kr) * HD) + kcb,                      \
            (char*)&kt[buf][0][0] + ((w * 4 + i) << 10) + (lane << 4));               \
      int vr = vr_l + 8 * i;                                                          \
      int vcb = vcb_base ^ ((vr & 7) << 4);                                           \
      GLL16((const char*)(vbh + (size_t)vr * S + (kv)) + vcb,                         \
            (char*)&vtl[buf][0][0] + ((w * 4 + i) << 10) + (lane << 4));              \
    }                                                                                 \
  }

  STAGE_KV(0, 0);                 // prologue: stage tile 0
  int cur = 0;
  for (int kv0 = 0; kv0 < kv_end; kv0 += 64) {
    __syncthreads();              // vmcnt(0) drain => buf[cur] staged; all waves done reading buf[cur^1]
    if (kv0 + 64 < kv_end) STAGE_KV(cur ^ 1, kv0 + 64);   // overlaps with this tile's compute
    // ---- QK^T (swizzled K reads) ----
    f32x4 sf[4] = {};
    int swz = (lr & 7) << 4;
    __builtin_amdgcn_s_setprio(1);
#pragma unroll
    for (int dstep = 0; dstep < 4; ++dstep)
#pragma unroll
      for (int nt = 0; nt < 4; ++nt) {
        int cb = ((dstep << 6) + (lg << 4)) ^ swz;
        s16x8 bk = *(const s16x8*)((const char*)&kt[cur][nt * 16 + lr][0] + cb);
        sf[nt] = MFMA16(aq[dstep], bk, sf[nt], 0, 0, 0);
      }
    __builtin_amdgcn_s_setprio(0);
    // ---- online softmax (stage-major reduces) ----
    int grow0 = q0 + w * 16 + lg * 4;
    float pmax[4] = {-INFINITY, -INFINITY, -INFINITY, -INFINITY};
#pragma unroll
    for (int nt = 0; nt < 4; ++nt) {
      int col = kv0 + nt * 16 + lr;
#pragma unroll
      for (int r = 0; r < 4; ++r) {
        float sv = sf[nt][r] * scale;
        if (col > grow0 + r) sv = -INFINITY;
        sf[nt][r] = sv;
        pmax[r] = fmaxf(pmax[r], sv);
      }
    }
#pragma unroll
    for (int off = 1; off < 16; off <<= 1)
#pragma unroll
      for (int r = 0; r < 4; ++r) pmax[r] = fmaxf(pmax[r], __shfl_xor(pmax[r], off));
    float alpha[4], ps[4];
#pragma unroll
    for (int r = 0; r < 4; ++r) {
      float mn = fmaxf(mrow[r], pmax[r]);
      alpha[r] = __expf(mrow[r] - mn);
      mrow[r] = mn;
      ps[r] = 0.f;
#pragma unroll
      for (int nt = 0; nt < 4; ++nt) { float e = __expf(sf[nt][r] - mn); sf[nt][r] = e; ps[r] += e; }
    }
#pragma unroll
    for (int off = 1; off < 16; off <<= 1)
#pragma unroll
      for (int r = 0; r < 4; ++r) ps[r] += __shfl_xor(ps[r], off);
#pragma unroll
    for (int r = 0; r < 4; ++r) {
      lsum[r] = lsum[r] * alpha[r] + ps[r];
#pragma unroll
      for (int dt = 0; dt < 8; ++dt) o[dt][r] *= alpha[r];
    }
    // ---- P -> bf16 via per-wave LDS (A-fragment relayout) ----
#pragma unroll
    for (int nt = 0; nt < 4; ++nt)
#pragma unroll
      for (int r = 0; r < 4; ++r)
        pl[w][lg * 4 + r][nt * 16 + lr] = f2b(sf[nt][r]);
    asm volatile("s_waitcnt lgkmcnt(0)" ::: "memory");
    __builtin_amdgcn_sched_barrier(0);
    s16x8 pa0 = *(const s16x8*)&pl[w][lr][lg * 8];
    s16x8 pa1 = *(const s16x8*)&pl[w][lr][32 + lg * 8];
    // ---- PV (swizzled V reads) ----
    __builtin_amdgcn_s_setprio(1);
#pragma unroll
    for (int dt = 0; dt < 8; ++dt) {
      int cb0 = (lg << 4) ^ swz;
      int cb1 = (64 + (lg << 4)) ^ swz;
      s16x8 bv0 = *(const s16x8*)((const char*)&vtl[cur][dt * 16 + lr][0] + cb0);
      s16x8 bv1 = *(const s16x8*)((const char*)&vtl[cur][dt * 16 + lr][0] + cb1);
      o[dt] = MFMA16(pa0, bv0, o[dt], 0, 0, 0);
      o[dt] = MFMA16(pa1, bv1, o[dt], 0, 0, 0);
    }
    __builtin_amdgcn_s_setprio(0);
    cur ^= 1;
  }
#undef STAGE_KV
  int b = bh >> 4, h = bh & 15;
#pragma unroll
  for (int dt = 0; dt < 8; ++dt)
#pragma unroll
    for (int r = 0; r < 4; ++r) {
      int srow = q0 + w * 16 + lg * 4 + r;
      float val = o[dt][r] / lsum[r];
      y[((size_t)(b * 2048 + srow)) * 2048 + h * 128 + dt * 16 + lr] = f2b(val);
    }
}

extern "C" void kernel_launch(void* const* d_in, const int* in_sizes, int n_in,
                              void* d_out, int out_size, void* d_ws, size_t ws_size,
                              hipStream_t stream) {
  const float* x    = (const float*)d_in[0];
  const float* wqkv = (const float*)d_in[1];
  const float* wo   = (const float*)d_in[2];
  float* out = (float*)d_out;
  char* ws = (char*)d_ws;
  u16* xb    = (u16*)(ws);                           // 16 MB: x bf16 (4096x2048)
  u16* wqkvt = (u16*)(ws + (size_t)(16)  * 1048576); // 24 MB: Wqkv^T (6144x2048)
  u16* wot   = (u16*)(ws + (size_t)(40)  * 1048576); //  8 MB: Wo^T (2048x2048)
  u16* qb    = (u16*)(ws + (size_t)(48)  * 1048576); // 16 MB: q (B,H,S,128)
  u16* kb    = (u16*)(ws + (size_t)(64)  * 1048576); // 16 MB: k
  u16* vb    = (u16*)(ws + (size_t)(80)  * 1048576); // 16 MB: v
  u16* vtb   = (u16*)(ws + (size_t)(96)  * 1048576); // 16 MB: v^T (B,H,128,S)
  u16* yb    = (u16*)(ws + (size_t)(112) * 1048576); // 16 MB: attn out (B,S,D)
  float2* trig = (float2*)(ws + (size_t)(128) * 1048576); // 1 MB

  k_cvt<<<8192, 256, 0, stream>>>(x, xb);
  k_tconv<<<dim3(96, 32), 256, 0, stream>>>(wqkv, wqkvt, 2048, 6144);
  k_tconv<<<dim3(32, 32), 256, 0, stream>>>(wo, wot, 2048, 2048);
  k_trig<<<512, 256, 0, stream>>>(trig);
  k_gemm8<0><<<dim3(24, 32), 512, 0, stream>>>(xb, wqkvt, qb, kb, vb, nullptr);
  k_rope<<<dim3(4096, 2), 256, 0, stream>>>(qb, kb, trig);
  k_trv<<<dim3(32, 2, 32), 256, 0, stream>>>(vb, vtb);
  k_attn<<<dim3(32, 32), 256, 0, stream>>>(qb, kb, vtb, yb);
  k_gemm8<1><<<dim3(8, 32), 512, 0, stream>>>(yb, wot, nullptr, nullptr, nullptr, out);
}

// Round 8
// 334.021 us; speedup vs baseline: 1.0573x; 1.0573x over previous
//
#include <hip/hip_runtime.h>
#include <hip/hip_bf16.h>

typedef __attribute__((ext_vector_type(4))) float f32x4;
typedef __attribute__((ext_vector_type(8))) short s16x8;
typedef unsigned short u16;
typedef unsigned int u32;

#define MFMA16 __builtin_amdgcn_mfma_f32_16x16x32_bf16

// global_load_lds: LDS dest is wave-uniform base + lane*16 (linear!), global src per-lane.
#define GLL16(g, l)                                                        \
  __builtin_amdgcn_global_load_lds(                                        \
      (const __attribute__((address_space(1))) void*)(g),                  \
      (__attribute__((address_space(3))) void*)(l), 16, 0, 0)

__device__ __forceinline__ u16 f2b(float f) {
  u32 x = __builtin_bit_cast(u32, f);
  u32 r = (x + 0x7fffu + ((x >> 16) & 1u)) >> 16;
  return (u16)r;
}
__device__ __forceinline__ float b2f(u16 u) {
  u32 x = ((u32)u) << 16;
  return __builtin_bit_cast(float, x);
}

// ---------- fp32 -> bf16 elementwise (x) ----------
__global__ __launch_bounds__(256) void k_cvt(const float* __restrict__ in, u16* __restrict__ out) {
  size_t i = ((size_t)blockIdx.x * 256 + threadIdx.x) * 4;
  float4 v = *(const float4*)(in + i);
  ushort4 o; o.x = f2b(v.x); o.y = f2b(v.y); o.z = f2b(v.z); o.w = f2b(v.w);
  *(ushort4*)(out + i) = o;
}

// ---------- transpose + convert: in (R x C) fp32 -> out (C x R) bf16 ----------
__global__ __launch_bounds__(256) void k_tconv(const float* __restrict__ in, u16* __restrict__ out,
                                               int R, int C) {
  __shared__ u16 tile[64][72];
  int c0 = blockIdx.x * 64, r0 = blockIdx.y * 64;
  int t = threadIdx.x;
#pragma unroll
  for (int p = 0; p < 4; ++p) {
    int idx = p * 1024 + t * 4;
    int row = idx >> 6, col = idx & 63;
    float4 v = *(const float4*)&in[(size_t)(r0 + row) * C + c0 + col];
    tile[row][col]     = f2b(v.x);
    tile[row][col + 1] = f2b(v.y);
    tile[row][col + 2] = f2b(v.z);
    tile[row][col + 3] = f2b(v.w);
  }
  __syncthreads();
#pragma unroll
  for (int p = 0; p < 4; ++p) {
    int idx = p * 1024 + t * 4;
    int row = idx >> 6, col = idx & 63;   // row: c-dim, col: r-dim
    ushort4 o;
    o.x = tile[col][row]; o.y = tile[col + 1][row];
    o.z = tile[col + 2][row]; o.w = tile[col + 3][row];
    *(ushort4*)&out[(size_t)(c0 + row) * R + r0 + col] = o;
  }
}

// ---------- bf16 transpose per (b,h): (2048 s x 128 d) -> (128 d x 2048 s) ----------
__global__ __launch_bounds__(256) void k_trv(const u16* __restrict__ v, u16* __restrict__ vt) {
  __shared__ u16 tile[64][72];
  int bh = blockIdx.z;
  int s0 = blockIdx.x * 64, d0 = blockIdx.y * 64;
  const u16* src = v + (size_t)bh * 2048 * 128;
  u16* dst = vt + (size_t)bh * 2048 * 128;
  int t = threadIdx.x;
#pragma unroll
  for (int p = 0; p < 4; ++p) {
    int idx = p * 1024 + t * 4;
    int row = idx >> 6, col = idx & 63;
    ushort4 x = *(const ushort4*)&src[(size_t)(s0 + row) * 128 + d0 + col];
    tile[row][col] = x.x; tile[row][col + 1] = x.y;
    tile[row][col + 2] = x.z; tile[row][col + 3] = x.w;
  }
  __syncthreads();
#pragma unroll
  for (int p = 0; p < 4; ++p) {
    int idx = p * 1024 + t * 4;
    int row = idx >> 6, col = idx & 63;   // row: d-local, col: s-local
    ushort4 o;
    o.x = tile[col][row]; o.y = tile[col + 1][row];
    o.z = tile[col + 2][row]; o.w = tile[col + 3][row];
    *(ushort4*)&dst[(size_t)(d0 + row) * 2048 + s0 + col] = o;
  }
}

// ---------- RoPE trig table ----------
__global__ __launch_bounds__(256) void k_trig(float2* __restrict__ tab) {
  int t = blockIdx.x * 256 + threadIdx.x;      // 2048*64
  int s = t >> 6, i = t & 63;
  float inv = expf(-(float)i * (9.210340371976184f / 64.f)); // ln(10000)
  float a = (float)s * inv;
  float sn, cs;
  sincosf(a, &sn, &cs);
  tab[t] = make_float2(cs, sn);
}

// ---------- RoPE in-place on q (y=0) / k (y=1), (B*H, S, 128) bf16 ----------
__global__ __launch_bounds__(256) void k_rope(u16* __restrict__ q, u16* __restrict__ k,
                                              const float2* __restrict__ tab) {
  u16* ptr = blockIdx.y ? k : q;
  size_t tid = (size_t)blockIdx.x * 256 + threadIdx.x;  // 32*2048*16
  int g = (int)(tid & 15);
  int s = (int)((tid >> 4) & 2047);
  int bh = (int)(tid >> 15);
  size_t base = ((size_t)bh * 2048 + s) * 128 + (size_t)g * 8;
  uint4 dv = *(const uint4*)(ptr + base);
  u16* pu = (u16*)&dv;
  const float2* tb = &tab[s * 64 + g * 4];
#pragma unroll
  for (int j = 0; j < 4; ++j) {
    float xe = b2f(pu[2 * j]), xo = b2f(pu[2 * j + 1]);
    float c = tb[j].x, sn = tb[j].y;
    pu[2 * j]     = f2b(xe * c - xo * sn);
    pu[2 * j + 1] = f2b(xe * sn + xo * c);
  }
  *(uint4*)(ptr + base) = dv;
}

// ---------- GEMM (T2+T3+T4+T5): BM=128, BN=256, BK=64, 8 waves, 3-buf counted vmcnt ----------
// Identity block mapping (NO XCD swizzle): x-major dispatch with gridDim.x % 8 == 0 gives each
// XCD a stable set of n-panels (n = xcd mod 8) that stays L2-resident across all m-rows.
// Pipeline: 3 staging buffers; step t stages tile t+2 and waits vmcnt(6) (tile t done, t+1 in
// flight) — never drains to 0 in steady state (T4).
// LDS XOR swizzle (rule #21): linear GLL dest + inverse-swizzled global source + same XOR on read.
template <int MODE>
__global__ __launch_bounds__(512) void k_gemm8(const u16* __restrict__ A, const u16* __restrict__ Bt,
                                               u16* __restrict__ qo, u16* __restrict__ ko,
                                               u16* __restrict__ vo, float* __restrict__ C) {
  constexpr int K = 2048;
  constexpr int NT = K / 64;
  __shared__ u16 sA[3][128 * 64];   // 3 x 16 KB
  __shared__ u16 sB[3][256 * 64];   // 3 x 32 KB
  int tid = threadIdx.x;
  int lane = tid & 63, w = tid >> 6;
  int wr = w >> 2, wc = w & 3;               // 2(M) x 4(N) wave grid, 64x64 per wave
  int lr = lane & 15, lg = lane >> 4;

  int n0 = blockIdx.x * 256;
  int m0 = blockIdx.y * 128;

  // staging: per GLL round, thread covers row = r*64 + tid>>3, linear col byte (tid&7)*16;
  // global source col pre-swizzled by ((row&7)<<4) = ((tid>>3)&7)<<4 (rounds are 64-row aligned)
  int srow = tid >> 3;
  int swzcolb = ((tid & 7) << 4) ^ ((srow & 7) << 4);
  const char* gA = (const char*)(A + (size_t)(m0 + srow) * K) + swzcolb;
  const char* gB = (const char*)(Bt + (size_t)(n0 + srow) * K) + swzcolb;

#define STAGE8(buf, k0)                                                      \
  {                                                                          \
    _Pragma("unroll") for (int rb = 0; rb < 4; ++rb)                         \
        GLL16(gB + ((size_t)rb * 64 * K + (k0)) * 2,                         \
              (char*)&sB[buf][0] + rb * 8192 + tid * 16);                    \
    _Pragma("unroll") for (int ra = 0; ra < 2; ++ra)                         \
        GLL16(gA + ((size_t)ra * 64 * K + (k0)) * 2,                         \
              (char*)&sA[buf][0] + ra * 8192 + tid * 16);                    \
  }

  // fragment read addressing: row = {wr|wc}*64 + i*16 + lr (row&7 == lr&7);
  // physical col byte = (ks*64 | lg*16) ^ ((lr&7)<<4) = colb0 ^ (ks<<6)
  int colb0 = (lg << 4) ^ ((lr & 7) << 4);
  int aRowByte = (wr * 64 + lr) * 128;
  int bRowByte = (wc * 64 + lr) * 128;

  f32x4 acc[4][4] = {};

  STAGE8(0, 0);
  STAGE8(1, 64);

  for (int t = 0; t < NT; ++t) {
    int cur = t % 3;
    const char* sAb = (const char*)&sA[0][0] + cur * (128 * 64 * 2);
    const char* sBb = (const char*)&sB[0][0] + cur * (256 * 64 * 2);
    // wait tile t staged (leave tile t+1's 6 loads in flight — T4 counted vmcnt)
    if (t + 1 < NT) { asm volatile("s_waitcnt vmcnt(6)" ::: "memory"); }
    else            { asm volatile("s_waitcnt vmcnt(0)" ::: "memory"); }
    __builtin_amdgcn_s_barrier();        // all waves' tile-t loads landed; buf[(t+2)%3] free
    if (t + 2 < NT) STAGE8((t + 2) % 3, (t + 2) * 64);
    s16x8 af[4], bf[4];
    // ---- phase 0 (ks=0) ----
#pragma unroll
    for (int i = 0; i < 4; ++i) af[i] = *(const s16x8*)(sAb + aRowByte + i * 2048 + colb0);
#pragma unroll
    for (int i = 0; i < 4; ++i) bf[i] = *(const s16x8*)(sBb + bRowByte + i * 2048 + colb0);
    __builtin_amdgcn_s_barrier();
    asm volatile("s_waitcnt lgkmcnt(0)" ::: "memory");
    __builtin_amdgcn_sched_barrier(0);
    __builtin_amdgcn_s_setprio(1);
#pragma unroll
    for (int mi = 0; mi < 4; ++mi)
#pragma unroll
      for (int ni = 0; ni < 4; ++ni)
        acc[mi][ni] = MFMA16(af[mi], bf[ni], acc[mi][ni], 0, 0, 0);
    __builtin_amdgcn_s_setprio(0);
    __builtin_amdgcn_s_barrier();
    // ---- phase 1 (ks=1) ----
#pragma unroll
    for (int i = 0; i < 4; ++i) af[i] = *(const s16x8*)(sAb + aRowByte + i * 2048 + (colb0 ^ 64));
#pragma unroll
    for (int i = 0; i < 4; ++i) bf[i] = *(const s16x8*)(sBb + bRowByte + i * 2048 + (colb0 ^ 64));
    __builtin_amdgcn_s_barrier();
    asm volatile("s_waitcnt lgkmcnt(0)" ::: "memory");
    __builtin_amdgcn_sched_barrier(0);
    __builtin_amdgcn_s_setprio(1);
#pragma unroll
    for (int mi = 0; mi < 4; ++mi)
#pragma unroll
      for (int ni = 0; ni < 4; ++ni)
        acc[mi][ni] = MFMA16(af[mi], bf[ni], acc[mi][ni], 0, 0, 0);
    __builtin_amdgcn_s_setprio(0);
  }
#undef STAGE8

  if constexpr (MODE == 0) {
#pragma unroll
    for (int ni = 0; ni < 4; ++ni) {
      int n = n0 + wc * 64 + ni * 16 + lr;
      int which = n >> 11;
      int h = (n >> 7) & 15;
      int d = n & 127;
      u16* dst = which == 0 ? qo : (which == 1 ? ko : vo);
#pragma unroll
      for (int mi = 0; mi < 4; ++mi)
#pragma unroll
        for (int r = 0; r < 4; ++r) {
          int m = m0 + wr * 64 + mi * 16 + lg * 4 + r;
          int b = m >> 11, s = m & 2047;
          dst[(((size_t)b * 16 + h) * 2048 + s) * 128 + d] = f2b(acc[mi][ni][r]);
        }
    }
  } else {
#pragma unroll
    for (int mi = 0; mi < 4; ++mi)
#pragma unroll
      for (int ni = 0; ni < 4; ++ni)
#pragma unroll
        for (int r = 0; r < 4; ++r) {
          int m = m0 + wr * 64 + mi * 16 + lg * 4 + r;
          int n = n0 + wc * 64 + ni * 16 + lr;
          C[(size_t)m * 2048 + n] = acc[mi][ni][r];
        }
  }
}

// ---------- Flash attention (causal): GLL double-buffered K/V staging ----------
__global__ __launch_bounds__(256) void k_attn(const u16* __restrict__ q, const u16* __restrict__ k,
                                              const u16* __restrict__ vt, u16* __restrict__ y) {
  constexpr int S = 2048, HD = 128;
  __shared__ u16 kt[2][64][128];   // 2 x 16 KB (kv x d), linear
  __shared__ u16 vtl[2][128][64];  // 2 x 16 KB (d x kv), linear
  __shared__ u16 pl[4][16][72];    // per-wave P (16 q x 64 kv)
  int bh = blockIdx.x;
  int qt = (gridDim.y - 1) - blockIdx.y;   // biggest q-tiles dispatched first (LPT)
  int q0 = qt * 64;
  int t = threadIdx.x, lane = t & 63, w = t >> 6;
  int lr = lane & 15, lg = lane >> 4;
  const size_t base = (size_t)bh * S * HD;
  const u16* kbh = k + base;
  const u16* vbh = vt + base;

  int kr_l = ((w * 4) << 2) + (lane >> 4);          // K row for instr i=0 (add 4*i)
  int kcb_base = (lane & 15) << 4;                  // linear byte col in K row
  int vr_l = ((w * 4) << 3) + (lane >> 3);          // V row for instr i=0 (add 8*i)
  int vcb_base = (lane & 7) << 4;                   // linear byte col in V row

  s16x8 aq[4];
  {
    size_t qrow = base + (size_t)(q0 + w * 16 + lr) * HD;
#pragma unroll
    for (int i = 0; i < 4; ++i) aq[i] = *(const s16x8*)&q[qrow + i * 32 + lg * 8];
  }
  f32x4 o[8] = {};
  float mrow[4] = {-INFINITY, -INFINITY, -INFINITY, -INFINITY};
  float lsum[4] = {};
  const float scale = 0.08838834764831845f;
  int kv_end = q0 + 64;

#define STAGE_KV(buf, kv)                                                             \
  {                                                                                   \
    _Pragma("unroll")                                                                 \
    for (int i = 0; i < 4; ++i) {                                                     \
      int kr = kr_l + 4 * i;                                                          \
      int kcb = kcb_base ^ ((kr & 7) << 4);                                           \
      GLL16((const char*)(kbh + (size_t)((kv) + kr) * HD) + kcb,                      \
            (char*)&kt[buf][0][0] + ((w * 4 + i) << 10) + (lane << 4));               \
      int vr = vr_l + 8 * i;                                                          \
      int vcb = vcb_base ^ ((vr & 7) << 4);                                           \
      GLL16((const char*)(vbh + (size_t)vr * S + (kv)) + vcb,                         \
            (char*)&vtl[buf][0][0] + ((w * 4 + i) << 10) + (lane << 4));              \
    }                                                                                 \
  }

  STAGE_KV(0, 0);                 // prologue: stage tile 0
  int cur = 0;
  for (int kv0 = 0; kv0 < kv_end; kv0 += 64) {
    __syncthreads();              // vmcnt(0) drain => buf[cur] staged; all waves done reading buf[cur^1]
    if (kv0 + 64 < kv_end) STAGE_KV(cur ^ 1, kv0 + 64);   // overlaps with this tile's compute
    // ---- QK^T (swizzled K reads) ----
    f32x4 sf[4] = {};
    int swz = (lr & 7) << 4;
    __builtin_amdgcn_s_setprio(1);
#pragma unroll
    for (int dstep = 0; dstep < 4; ++dstep)
#pragma unroll
      for (int nt = 0; nt < 4; ++nt) {
        int cb = ((dstep << 6) + (lg << 4)) ^ swz;
        s16x8 bk = *(const s16x8*)((const char*)&kt[cur][nt * 16 + lr][0] + cb);
        sf[nt] = MFMA16(aq[dstep], bk, sf[nt], 0, 0, 0);
      }
    __builtin_amdgcn_s_setprio(0);
    // ---- online softmax (stage-major reduces) ----
    int grow0 = q0 + w * 16 + lg * 4;
    float pmax[4] = {-INFINITY, -INFINITY, -INFINITY, -INFINITY};
#pragma unroll
    for (int nt = 0; nt < 4; ++nt) {
      int col = kv0 + nt * 16 + lr;
#pragma unroll
      for (int r = 0; r < 4; ++r) {
        float sv = sf[nt][r] * scale;
        if (col > grow0 + r) sv = -INFINITY;
        sf[nt][r] = sv;
        pmax[r] = fmaxf(pmax[r], sv);
      }
    }
#pragma unroll
    for (int off = 1; off < 16; off <<= 1)
#pragma unroll
      for (int r = 0; r < 4; ++r) pmax[r] = fmaxf(pmax[r], __shfl_xor(pmax[r], off));
    float alpha[4], ps[4];
#pragma unroll
    for (int r = 0; r < 4; ++r) {
      float mn = fmaxf(mrow[r], pmax[r]);
      alpha[r] = __expf(mrow[r] - mn);
      mrow[r] = mn;
      ps[r] = 0.f;
#pragma unroll
      for (int nt = 0; nt < 4; ++nt) { float e = __expf(sf[nt][r] - mn); sf[nt][r] = e; ps[r] += e; }
    }
#pragma unroll
    for (int off = 1; off < 16; off <<= 1)
#pragma unroll
      for (int r = 0; r < 4; ++r) ps[r] += __shfl_xor(ps[r], off);
#pragma unroll
    for (int r = 0; r < 4; ++r) {
      lsum[r] = lsum[r] * alpha[r] + ps[r];
#pragma unroll
      for (int dt = 0; dt < 8; ++dt) o[dt][r] *= alpha[r];
    }
    // ---- P -> bf16 via per-wave LDS (A-fragment relayout) ----
#pragma unroll
    for (int nt = 0; nt < 4; ++nt)
#pragma unroll
      for (int r = 0; r < 4; ++r)
        pl[w][lg * 4 + r][nt * 16 + lr] = f2b(sf[nt][r]);
    asm volatile("s_waitcnt lgkmcnt(0)" ::: "memory");
    __builtin_amdgcn_sched_barrier(0);
    s16x8 pa0 = *(const s16x8*)&pl[w][lr][lg * 8];
    s16x8 pa1 = *(const s16x8*)&pl[w][lr][32 + lg * 8];
    // ---- PV (swizzled V reads) ----
    __builtin_amdgcn_s_setprio(1);
#pragma unroll
    for (int dt = 0; dt < 8; ++dt) {
      int cb0 = (lg << 4) ^ swz;
      int cb1 = (64 + (lg << 4)) ^ swz;
      s16x8 bv0 = *(const s16x8*)((const char*)&vtl[cur][dt * 16 + lr][0] + cb0);
      s16x8 bv1 = *(const s16x8*)((const char*)&vtl[cur][dt * 16 + lr][0] + cb1);
      o[dt] = MFMA16(pa0, bv0, o[dt], 0, 0, 0);
      o[dt] = MFMA16(pa1, bv1, o[dt], 0, 0, 0);
    }
    __builtin_amdgcn_s_setprio(0);
    cur ^= 1;
  }
#undef STAGE_KV
  int b = bh >> 4, h = bh & 15;
#pragma unroll
  for (int dt = 0; dt < 8; ++dt)
#pragma unroll
    for (int r = 0; r < 4; ++r) {
      int srow = q0 + w * 16 + lg * 4 + r;
      float val = o[dt][r] / lsum[r];
      y[((size_t)(b * 2048 + srow)) * 2048 + h * 128 + dt * 16 + lr] = f2b(val);
    }
}

extern "C" void kernel_launch(void* const* d_in, const int* in_sizes, int n_in,
                              void* d_out, int out_size, void* d_ws, size_t ws_size,
                              hipStream_t stream) {
  const float* x    = (const float*)d_in[0];
  const float* wqkv = (const float*)d_in[1];
  const float* wo   = (const float*)d_in[2];
  float* out = (float*)d_out;
  char* ws = (char*)d_ws;
  u16* xb    = (u16*)(ws);                           // 16 MB: x bf16 (4096x2048)
  u16* wqkvt = (u16*)(ws + (size_t)(16)  * 1048576); // 24 MB: Wqkv^T (6144x2048)
  u16* wot   = (u16*)(ws + (size_t)(40)  * 1048576); //  8 MB: Wo^T (2048x2048)
  u16* qb    = (u16*)(ws + (size_t)(48)  * 1048576); // 16 MB: q (B,H,S,128)
  u16* kb    = (u16*)(ws + (size_t)(64)  * 1048576); // 16 MB: k
  u16* vb    = (u16*)(ws + (size_t)(80)  * 1048576); // 16 MB: v
  u16* vtb   = (u16*)(ws + (size_t)(96)  * 1048576); // 16 MB: v^T (B,H,128,S)
  u16* yb    = (u16*)(ws + (size_t)(112) * 1048576); // 16 MB: attn out (B,S,D)
  float2* trig = (float2*)(ws + (size_t)(128) * 1048576); // 1 MB

  k_cvt<<<8192, 256, 0, stream>>>(x, xb);
  k_tconv<<<dim3(96, 32), 256, 0, stream>>>(wqkv, wqkvt, 2048, 6144);
  k_tconv<<<dim3(32, 32), 256, 0, stream>>>(wo, wot, 2048, 2048);
  k_trig<<<512, 256, 0, stream>>>(trig);
  k_gemm8<0><<<dim3(24, 32), 512, 0, stream>>>(xb, wqkvt, qb, kb, vb, nullptr);
  k_rope<<<dim3(4096, 2), 256, 0, stream>>>(qb, kb, trig);
  k_trv<<<dim3(32, 2, 32), 256, 0, stream>>>(vb, vtb);
  k_attn<<<dim3(32, 32), 256, 0, stream>>>(qb, kb, vtb, yb);
  k_gemm8<1><<<dim3(8, 32), 512, 0, stream>>>(yb, wot, nullptr, nullptr, nullptr, out);
}

// Round 9
// 285.518 us; speedup vs baseline: 1.2370x; 1.1699x over previous
//
#include <hip/hip_runtime.h>
#include <hip/hip_bf16.h>

typedef __attribute__((ext_vector_type(4))) float f32x4;
typedef __attribute__((ext_vector_type(8))) short s16x8;
typedef unsigned short u16;
typedef unsigned int u32;

#define MFMA16 __builtin_amdgcn_mfma_f32_16x16x32_bf16

// global_load_lds: LDS dest is wave-uniform base + lane*16 (linear!), global src per-lane.
#define GLL16(g, l)                                                        \
  __builtin_amdgcn_global_load_lds(                                        \
      (const __attribute__((address_space(1))) void*)(g),                  \
      (__attribute__((address_space(3))) void*)(l), 16, 0, 0)

__device__ __forceinline__ u16 f2b(float f) {
  u32 x = __builtin_bit_cast(u32, f);
  u32 r = (x + 0x7fffu + ((x >> 16) & 1u)) >> 16;
  return (u16)r;
}
__device__ __forceinline__ float b2f(u16 u) {
  u32 x = ((u32)u) << 16;
  return __builtin_bit_cast(float, x);
}

// ---------- fp32 -> bf16 elementwise (x) ----------
__global__ __launch_bounds__(256) void k_cvt(const float* __restrict__ in, u16* __restrict__ out) {
  size_t i = ((size_t)blockIdx.x * 256 + threadIdx.x) * 4;
  float4 v = *(const float4*)(in + i);
  ushort4 o; o.x = f2b(v.x); o.y = f2b(v.y); o.z = f2b(v.z); o.w = f2b(v.w);
  *(ushort4*)(out + i) = o;
}

// ---------- transpose + convert: in (R x C) fp32 -> out (C x R) bf16 ----------
__global__ __launch_bounds__(256) void k_tconv(const float* __restrict__ in, u16* __restrict__ out,
                                               int R, int C) {
  __shared__ u16 tile[64][72];
  int c0 = blockIdx.x * 64, r0 = blockIdx.y * 64;
  int t = threadIdx.x;
#pragma unroll
  for (int p = 0; p < 4; ++p) {
    int idx = p * 1024 + t * 4;
    int row = idx >> 6, col = idx & 63;
    float4 v = *(const float4*)&in[(size_t)(r0 + row) * C + c0 + col];
    tile[row][col]     = f2b(v.x);
    tile[row][col + 1] = f2b(v.y);
    tile[row][col + 2] = f2b(v.z);
    tile[row][col + 3] = f2b(v.w);
  }
  __syncthreads();
#pragma unroll
  for (int p = 0; p < 4; ++p) {
    int idx = p * 1024 + t * 4;
    int row = idx >> 6, col = idx & 63;   // row: c-dim, col: r-dim
    ushort4 o;
    o.x = tile[col][row]; o.y = tile[col + 1][row];
    o.z = tile[col + 2][row]; o.w = tile[col + 3][row];
    *(ushort4*)&out[(size_t)(c0 + row) * R + r0 + col] = o;
  }
}

// ---------- bf16 transpose per (b,h): (2048 s x 128 d) -> (128 d x 2048 s) ----------
__global__ __launch_bounds__(256) void k_trv(const u16* __restrict__ v, u16* __restrict__ vt) {
  __shared__ u16 tile[64][72];
  int bh = blockIdx.z;
  int s0 = blockIdx.x * 64, d0 = blockIdx.y * 64;
  const u16* src = v + (size_t)bh * 2048 * 128;
  u16* dst = vt + (size_t)bh * 2048 * 128;
  int t = threadIdx.x;
#pragma unroll
  for (int p = 0; p < 4; ++p) {
    int idx = p * 1024 + t * 4;
    int row = idx >> 6, col = idx & 63;
    ushort4 x = *(const ushort4*)&src[(size_t)(s0 + row) * 128 + d0 + col];
    tile[row][col] = x.x; tile[row][col + 1] = x.y;
    tile[row][col + 2] = x.z; tile[row][col + 3] = x.w;
  }
  __syncthreads();
#pragma unroll
  for (int p = 0; p < 4; ++p) {
    int idx = p * 1024 + t * 4;
    int row = idx >> 6, col = idx & 63;   // row: d-local, col: s-local
    ushort4 o;
    o.x = tile[col][row]; o.y = tile[col + 1][row];
    o.z = tile[col + 2][row]; o.w = tile[col + 3][row];
    *(ushort4*)&dst[(size_t)(d0 + row) * 2048 + s0 + col] = o;
  }
}

// ---------- RoPE trig table ----------
__global__ __launch_bounds__(256) void k_trig(float2* __restrict__ tab) {
  int t = blockIdx.x * 256 + threadIdx.x;      // 2048*64
  int s = t >> 6, i = t & 63;
  float inv = expf(-(float)i * (9.210340371976184f / 64.f)); // ln(10000)
  float a = (float)s * inv;
  float sn, cs;
  sincosf(a, &sn, &cs);
  tab[t] = make_float2(cs, sn);
}

// ---------- RoPE in-place on q (y=0) / k (y=1), (B*H, S, 128) bf16 ----------
__global__ __launch_bounds__(256) void k_rope(u16* __restrict__ q, u16* __restrict__ k,
                                              const float2* __restrict__ tab) {
  u16* ptr = blockIdx.y ? k : q;
  size_t tid = (size_t)blockIdx.x * 256 + threadIdx.x;  // 32*2048*16
  int g = (int)(tid & 15);
  int s = (int)((tid >> 4) & 2047);
  int bh = (int)(tid >> 15);
  size_t base = ((size_t)bh * 2048 + s) * 128 + (size_t)g * 8;
  uint4 dv = *(const uint4*)(ptr + base);
  u16* pu = (u16*)&dv;
  const float2* tb = &tab[s * 64 + g * 4];
#pragma unroll
  for (int j = 0; j < 4; ++j) {
    float xe = b2f(pu[2 * j]), xo = b2f(pu[2 * j + 1]);
    float c = tb[j].x, sn = tb[j].y;
    pu[2 * j]     = f2b(xe * c - xo * sn);
    pu[2 * j + 1] = f2b(xe * sn + xo * c);
  }
  *(uint4*)(ptr + base) = dv;
}

// ---------- GEMM (m97 structure + BK=64 + XOR swizzle): 128x128 tile, 4 waves, single-buf ----------
// Known-good m97 sync shape (sync; GLL; sync(drain); compute) — 5 blocks/CU of cross-block TLP
// hides the drain. BK=64 halves the number of exposed drains vs BK=32. 32 KB LDS keeps occupancy
// (m132: 64 KB -> 2 blocks/CU regressed). Identity block mapping: gridDim.x % 8 == 0 keeps each
// XCD's n-panels L2-resident. Swizzle (R8-proven, conflicts->0): linear GLL dest + pre-swizzled
// global source + byte ^= ((row&7)<<4) on read.
// MODE 0: scatter bf16 into q/k/v (B,H,S,128), n-tile==head; MODE 1: fp32 C.
template <int MODE>
__global__ __launch_bounds__(256) void k_gemm97b(const u16* __restrict__ A, const u16* __restrict__ Bt,
                                                 u16* __restrict__ qo, u16* __restrict__ ko,
                                                 u16* __restrict__ vo, float* __restrict__ C) {
  constexpr int K = 2048;
  __shared__ u16 sa[128 * 64];   // 16 KB, linear
  __shared__ u16 sb[128 * 64];   // 16 KB, linear
  int tid = threadIdx.x;
  int lane = tid & 63, w = tid >> 6;
  int wm = (w >> 1) * 64, wn = (w & 1) * 64;
  int lr = lane & 15, lg = lane >> 4;
  int n0 = blockIdx.x * 128;
  int m0 = blockIdx.y * 128;

  // staging: round r covers row = r*32 + (tid>>3), dest byte = r*4096 + tid*16 (linear);
  // src col byte pre-swizzled: (tid&7)*16 ^ ((row&7)<<4), row&7 == (tid>>3)&7 for all rounds
  int srow = tid >> 3;
  int swzb = ((tid & 7) << 4) ^ ((srow & 7) << 4);
  const char* gA = (const char*)(A + (size_t)(m0 + srow) * K) + swzb;
  const char* gB = (const char*)(Bt + (size_t)(n0 + srow) * K) + swzb;

  // fragment read: row = {wm|wn} + i*16 + lr (row&7 == lr&7);
  // byte col = (ks*64 + lg*16) ^ ((lr&7)<<4)
  int colb0 = (lg << 4) ^ ((lr & 7) << 4);
  int aRowB = (wm + lr) * 128;
  int bRowB = (wn + lr) * 128;

  f32x4 acc[4][4] = {};
  for (int k0 = 0; k0 < K; k0 += 64) {
    __syncthreads();
#pragma unroll
    for (int r = 0; r < 4; ++r) {
      GLL16(gA + ((size_t)(r * 32) * K + k0) * 2, (char*)sa + r * 4096 + tid * 16);
      GLL16(gB + ((size_t)(r * 32) * K + k0) * 2, (char*)sb + r * 4096 + tid * 16);
    }
    __syncthreads();   // drains vmcnt+lgkm — LDS ready (m97's known exposed cost, TLP-hidden)
#pragma unroll
    for (int ks = 0; ks < 2; ++ks) {
      int cb = colb0 ^ (ks << 6);
      s16x8 af[4], bf[4];
#pragma unroll
      for (int i = 0; i < 4; ++i) af[i] = *(const s16x8*)((const char*)sa + aRowB + i * 2048 + cb);
#pragma unroll
      for (int i = 0; i < 4; ++i) bf[i] = *(const s16x8*)((const char*)sb + bRowB + i * 2048 + cb);
#pragma unroll
      for (int mi = 0; mi < 4; ++mi)
#pragma unroll
        for (int ni = 0; ni < 4; ++ni)
          acc[mi][ni] = MFMA16(af[mi], bf[ni], acc[mi][ni], 0, 0, 0);
    }
  }

  if constexpr (MODE == 0) {
    int which = blockIdx.x >> 4;
    int h = blockIdx.x & 15;
    u16* dst = which == 0 ? qo : (which == 1 ? ko : vo);
#pragma unroll
    for (int mi = 0; mi < 4; ++mi)
#pragma unroll
      for (int ni = 0; ni < 4; ++ni)
#pragma unroll
        for (int r = 0; r < 4; ++r) {
          int m = m0 + wm + mi * 16 + lg * 4 + r;
          int d = wn + ni * 16 + lr;
          int b = m >> 11, s = m & 2047;
          dst[(((size_t)b * 16 + h) * 2048 + s) * 128 + d] = f2b(acc[mi][ni][r]);
        }
  } else {
#pragma unroll
    for (int mi = 0; mi < 4; ++mi)
#pragma unroll
      for (int ni = 0; ni < 4; ++ni)
#pragma unroll
        for (int r = 0; r < 4; ++r) {
          int m = m0 + wm + mi * 16 + lg * 4 + r;
          int n = n0 + wn + ni * 16 + lr;
          C[(size_t)m * 2048 + n] = acc[mi][ni][r];
        }
  }
}

// ---------- Flash attention (causal): GLL double-buffered K/V staging ----------
__global__ __launch_bounds__(256) void k_attn(const u16* __restrict__ q, const u16* __restrict__ k,
                                              const u16* __restrict__ vt, u16* __restrict__ y) {
  constexpr int S = 2048, HD = 128;
  __shared__ u16 kt[2][64][128];   // 2 x 16 KB (kv x d), linear
  __shared__ u16 vtl[2][128][64];  // 2 x 16 KB (d x kv), linear
  __shared__ u16 pl[4][16][72];    // per-wave P (16 q x 64 kv)
  int bh = blockIdx.x;
  int qt = (gridDim.y - 1) - blockIdx.y;   // biggest q-tiles dispatched first (LPT)
  int q0 = qt * 64;
  int t = threadIdx.x, lane = t & 63, w = t >> 6;
  int lr = lane & 15, lg = lane >> 4;
  const size_t base = (size_t)bh * S * HD;
  const u16* kbh = k + base;
  const u16* vbh = vt + base;

  int kr_l = ((w * 4) << 2) + (lane >> 4);          // K row for instr i=0 (add 4*i)
  int kcb_base = (lane & 15) << 4;                  // linear byte col in K row
  int vr_l = ((w * 4) << 3) + (lane >> 3);          // V row for instr i=0 (add 8*i)
  int vcb_base = (lane & 7) << 4;                   // linear byte col in V row

  s16x8 aq[4];
  {
    size_t qrow = base + (size_t)(q0 + w * 16 + lr) * HD;
#pragma unroll
    for (int i = 0; i < 4; ++i) aq[i] = *(const s16x8*)&q[qrow + i * 32 + lg * 8];
  }
  f32x4 o[8] = {};
  float mrow[4] = {-INFINITY, -INFINITY, -INFINITY, -INFINITY};
  float lsum[4] = {};
  const float scale = 0.08838834764831845f;
  int kv_end = q0 + 64;

#define STAGE_KV(buf, kv)                                                             \
  {                                                                                   \
    _Pragma("unroll")                                                                 \
    for (int i = 0; i < 4; ++i) {                                                     \
      int kr = kr_l + 4 * i;                                                          \
      int kcb = kcb_base ^ ((kr & 7) << 4);                                           \
      GLL16((const char*)(kbh + (size_t)((kv) + kr) * HD) + kcb,                      \
            (char*)&kt[buf][0][0] + ((w * 4 + i) << 10) + (lane << 4));               \
      int vr = vr_l + 8 * i;                                                          \
      int vcb = vcb_base ^ ((vr & 7) << 4);                                           \
      GLL16((const char*)(vbh + (size_t)vr * S + (kv)) + vcb,                         \
            (char*)&vtl[buf][0][0] + ((w * 4 + i) << 10) + (lane << 4));              \
    }                                                                                 \
  }

  STAGE_KV(0, 0);                 // prologue: stage tile 0
  int cur = 0;
  for (int kv0 = 0; kv0 < kv_end; kv0 += 64) {
    __syncthreads();              // vmcnt(0) drain => buf[cur] staged; all waves done reading buf[cur^1]
    if (kv0 + 64 < kv_end) STAGE_KV(cur ^ 1, kv0 + 64);   // overlaps with this tile's compute
    // ---- QK^T (swizzled K reads) ----
    f32x4 sf[4] = {};
    int swz = (lr & 7) << 4;
    __builtin_amdgcn_s_setprio(1);
#pragma unroll
    for (int dstep = 0; dstep < 4; ++dstep)
#pragma unroll
      for (int nt = 0; nt < 4; ++nt) {
        int cb = ((dstep << 6) + (lg << 4)) ^ swz;
        s16x8 bk = *(const s16x8*)((const char*)&kt[cur][nt * 16 + lr][0] + cb);
        sf[nt] = MFMA16(aq[dstep], bk, sf[nt], 0, 0, 0);
      }
    __builtin_amdgcn_s_setprio(0);
    // ---- online softmax (stage-major reduces) ----
    int grow0 = q0 + w * 16 + lg * 4;
    float pmax[4] = {-INFINITY, -INFINITY, -INFINITY, -INFINITY};
#pragma unroll
    for (int nt = 0; nt < 4; ++nt) {
      int col = kv0 + nt * 16 + lr;
#pragma unroll
      for (int r = 0; r < 4; ++r) {
        float sv = sf[nt][r] * scale;
        if (col > grow0 + r) sv = -INFINITY;
        sf[nt][r] = sv;
        pmax[r] = fmaxf(pmax[r], sv);
      }
    }
#pragma unroll
    for (int off = 1; off < 16; off <<= 1)
#pragma unroll
      for (int r = 0; r < 4; ++r) pmax[r] = fmaxf(pmax[r], __shfl_xor(pmax[r], off));
    float alpha[4], ps[4];
#pragma unroll
    for (int r = 0; r < 4; ++r) {
      float mn = fmaxf(mrow[r], pmax[r]);
      alpha[r] = __expf(mrow[r] - mn);
      mrow[r] = mn;
      ps[r] = 0.f;
#pragma unroll
      for (int nt = 0; nt < 4; ++nt) { float e = __expf(sf[nt][r] - mn); sf[nt][r] = e; ps[r] += e; }
    }
#pragma unroll
    for (int off = 1; off < 16; off <<= 1)
#pragma unroll
      for (int r = 0; r < 4; ++r) ps[r] += __shfl_xor(ps[r], off);
#pragma unroll
    for (int r = 0; r < 4; ++r) {
      lsum[r] = lsum[r] * alpha[r] + ps[r];
#pragma unroll
      for (int dt = 0; dt < 8; ++dt) o[dt][r] *= alpha[r];
    }
    // ---- P -> bf16 via per-wave LDS (A-fragment relayout) ----
#pragma unroll
    for (int nt = 0; nt < 4; ++nt)
#pragma unroll
      for (int r = 0; r < 4; ++r)
        pl[w][lg * 4 + r][nt * 16 + lr] = f2b(sf[nt][r]);
    asm volatile("s_waitcnt lgkmcnt(0)" ::: "memory");
    __builtin_amdgcn_sched_barrier(0);
    s16x8 pa0 = *(const s16x8*)&pl[w][lr][lg * 8];
    s16x8 pa1 = *(const s16x8*)&pl[w][lr][32 + lg * 8];
    // ---- PV (swizzled V reads) ----
    __builtin_amdgcn_s_setprio(1);
#pragma unroll
    for (int dt = 0; dt < 8; ++dt) {
      int cb0 = (lg << 4) ^ swz;
      int cb1 = (64 + (lg << 4)) ^ swz;
      s16x8 bv0 = *(const s16x8*)((const char*)&vtl[cur][dt * 16 + lr][0] + cb0);
      s16x8 bv1 = *(const s16x8*)((const char*)&vtl[cur][dt * 16 + lr][0] + cb1);
      o[dt] = MFMA16(pa0, bv0, o[dt], 0, 0, 0);
      o[dt] = MFMA16(pa1, bv1, o[dt], 0, 0, 0);
    }
    __builtin_amdgcn_s_setprio(0);
    cur ^= 1;
  }
#undef STAGE_KV
  int b = bh >> 4, h = bh & 15;
#pragma unroll
  for (int dt = 0; dt < 8; ++dt)
#pragma unroll
    for (int r = 0; r < 4; ++r) {
      int srow = q0 + w * 16 + lg * 4 + r;
      float val = o[dt][r] / lsum[r];
      y[((size_t)(b * 2048 + srow)) * 2048 + h * 128 + dt * 16 + lr] = f2b(val);
    }
}

extern "C" void kernel_launch(void* const* d_in, const int* in_sizes, int n_in,
                              void* d_out, int out_size, void* d_ws, size_t ws_size,
                              hipStream_t stream) {
  const float* x    = (const float*)d_in[0];
  const float* wqkv = (const float*)d_in[1];
  const float* wo   = (const float*)d_in[2];
  float* out = (float*)d_out;
  char* ws = (char*)d_ws;
  u16* xb    = (u16*)(ws);                           // 16 MB: x bf16 (4096x2048)
  u16* wqkvt = (u16*)(ws + (size_t)(16)  * 1048576); // 24 MB: Wqkv^T (6144x2048)
  u16* wot   = (u16*)(ws + (size_t)(40)  * 1048576); //  8 MB: Wo^T (2048x2048)
  u16* qb    = (u16*)(ws + (size_t)(48)  * 1048576); // 16 MB: q (B,H,S,128)
  u16* kb    = (u16*)(ws + (size_t)(64)  * 1048576); // 16 MB: k
  u16* vb    = (u16*)(ws + (size_t)(80)  * 1048576); // 16 MB: v
  u16* vtb   = (u16*)(ws + (size_t)(96)  * 1048576); // 16 MB: v^T (B,H,128,S)
  u16* yb    = (u16*)(ws + (size_t)(112) * 1048576); // 16 MB: attn out (B,S,D)
  float2* trig = (float2*)(ws + (size_t)(128) * 1048576); // 1 MB

  k_cvt<<<8192, 256, 0, stream>>>(x, xb);
  k_tconv<<<dim3(96, 32), 256, 0, stream>>>(wqkv, wqkvt, 2048, 6144);
  k_tconv<<<dim3(32, 32), 256, 0, stream>>>(wo, wot, 2048, 2048);
  k_trig<<<512, 256, 0, stream>>>(trig);
  k_gemm97b<0><<<dim3(48, 32), 256, 0, stream>>>(xb, wqkvt, qb, kb, vb, nullptr);
  k_rope<<<dim3(4096, 2), 256, 0, stream>>>(qb, kb, trig);
  k_trv<<<dim3(32, 2, 32), 256, 0, stream>>>(vb, vtb);
  k_attn<<<dim3(32, 32), 256, 0, stream>>>(qb, kb, vtb, yb);
  k_gemm97b<1><<<dim3(16, 32), 256, 0, stream>>>(yb, wot, nullptr, nullptr, nullptr, out);
}